// Round 1
// baseline (372.841 us; speedup 1.0000x reference)
//
#include <hip/hip_runtime.h>

// J-statistic loss. Core identity: S[b,i,k] = T[b,i,k]/n[b,k] where
//   T[b,i,k] = sum over pixels p with target[b,p]==k of pred[b,i,p]
//   n[b,k]   = #pixels of class k in batch b
// j[b] = -sum_{i!=k} log(0.5 + 0.5*(T[b,i,i]/n[b,i] - T[b,i,k]/n[b,k]))
//
// Memory-bound: pred is 151 MB read-once; everything else is tiny.

#define BB 8
#define CC 32
#define HW 147456            // 384*384
#define CHUNK 1024           // pixels per block (256 threads x 4 pixels)
#define BLOCKS_PER_B (HW / CHUNK)   // 144

__global__ __launch_bounds__(256) void jloss_hist(
    const float* __restrict__ pred,    // [B][C][HW]
    const int*   __restrict__ target,  // [B][HW]
    float*       __restrict__ T,       // [B][C][C] (pre-zeroed)
    int*         __restrict__ cnt)     // [B][C]    (pre-zeroed)
{
    __shared__ float bins[CC * CC];
    __shared__ int   scnt[CC];

    const int tid   = threadIdx.x;
    const int blk   = blockIdx.x;
    const int b     = blk / BLOCKS_PER_B;
    const int chunk = blk % BLOCKS_PER_B;
    const long pbase = (long)chunk * CHUNK + (long)tid * 4;

    // zero LDS
    for (int j = tid; j < CC * CC; j += 256) bins[j] = 0.0f;
    if (tid < CC) scnt[tid] = 0;
    __syncthreads();

    // each thread owns 4 consecutive pixels; target read once, kept in regs
    const int4 t = *(const int4*)(target + (long)b * HW + pbase);
    atomicAdd(&scnt[t.x], 1);
    atomicAdd(&scnt[t.y], 1);
    atomicAdd(&scnt[t.z], 1);
    atomicAdd(&scnt[t.w], 1);

    const float* predb = pred + (long)b * CC * HW + pbase;
    #pragma unroll 4
    for (int i = 0; i < CC; ++i) {
        const float4 v = *(const float4*)(predb + (long)i * HW);  // coalesced 16B/lane
        float* row = &bins[i * CC];
        atomicAdd(&row[t.x], v.x);
        atomicAdd(&row[t.y], v.y);
        atomicAdd(&row[t.z], v.z);
        atomicAdd(&row[t.w], v.w);
    }
    __syncthreads();

    // flush block-local bins to global accumulators
    float* Tb = T + (long)b * CC * CC;
    for (int j = tid; j < CC * CC; j += 256) atomicAdd(&Tb[j], bins[j]);
    if (tid < CC) atomicAdd(&cnt[b * CC + tid], scnt[tid]);
}

__global__ __launch_bounds__(256) void jloss_final(
    const float* __restrict__ T,
    const int*   __restrict__ cnt,
    float*       __restrict__ out)
{
    const int b   = blockIdx.x;
    const int tid = threadIdx.x;
    __shared__ float diag_s[CC];
    __shared__ float inv_n[CC];
    __shared__ float wsum[4];

    const float* Tb = T + (long)b * CC * CC;
    const int*   cb = cnt + b * CC;

    if (tid < CC) {
        const float n = (float)cb[tid];
        const float inv = 1.0f / n;
        inv_n[tid]  = inv;
        diag_s[tid] = Tb[tid * CC + tid] * inv;
    }
    __syncthreads();

    float sum = 0.0f;
    for (int idx = tid; idx < CC * CC; idx += 256) {
        const int i = idx >> 5;
        const int k = idx & 31;
        if (i != k) {
            const float S = Tb[idx] * inv_n[k];
            sum += logf(0.5f + 0.5f * (diag_s[i] - S));
        }
    }
    // wave64 reduce
    #pragma unroll
    for (int off = 32; off > 0; off >>= 1) sum += __shfl_down(sum, off, 64);
    if ((tid & 63) == 0) wsum[tid >> 6] = sum;
    __syncthreads();
    if (tid == 0) out[b] = -(wsum[0] + wsum[1] + wsum[2] + wsum[3]);
}

extern "C" void kernel_launch(void* const* d_in, const int* in_sizes, int n_in,
                              void* d_out, int out_size, void* d_ws, size_t ws_size,
                              hipStream_t stream) {
    const float* pred   = (const float*)d_in[0];
    const int*   target = (const int*)d_in[1];
    float* out = (float*)d_out;

    float* T   = (float*)d_ws;                                   // 8*32*32 f32 = 32 KB
    int*   cnt = (int*)((char*)d_ws + BB * CC * CC * sizeof(float)); // 8*32 i32 = 1 KB

    hipMemsetAsync(d_ws, 0, BB * CC * CC * sizeof(float) + BB * CC * sizeof(int), stream);

    jloss_hist<<<BB * BLOCKS_PER_B, 256, 0, stream>>>(pred, target, T, cnt);
    jloss_final<<<BB, 256, 0, stream>>>(T, cnt, out);
}

// Round 2
// 268.376 us; speedup vs baseline: 1.3893x; 1.3893x over previous
//
#include <hip/hip_runtime.h>

// J-loss via MFMA: T[b,i,k] = sum_p pred[b,i,p] * onehot(target[b,p]==k)
//   = (32 x HW) . (HW x 32) bf16 GEMM per batch, one-hot built in registers.
// j[b] = -sum_{i!=k} log(0.5 + 0.5*(T[b,i,i]/n[b,i] - T[b,i,k]/n[b,k]))
// Round 1 post-mortem: LDS atomics serialized at ~1 lane-op/3.5cyc/CU -> 216us.
// This version has ZERO per-element atomics.

#define BB 8
#define CC 32
#define HW 147456                 // 384*384
#define CHUNK_PX 1024             // pixels per block
#define NCHUNK (HW / CHUNK_PX)    // 144
#define HIST_BPB 16
#define HIST_SEG (HW / HIST_BPB)  // 9216 px per hist block

typedef __attribute__((ext_vector_type(8))) short short8;
typedef __attribute__((ext_vector_type(4))) float float4v;

__device__ __forceinline__ short bf16_rne(float f) {
    union { float f; unsigned u; } v; v.f = f;
    unsigned u = v.u;
    u += 0x7FFFu + ((u >> 16) & 1u);   // round-to-nearest-even
    return (short)(u >> 16);
}

__global__ __launch_bounds__(256) void jloss_mfma(
    const float* __restrict__ pred,    // [B][C][HW]
    const int*   __restrict__ target,  // [B][HW]
    float*       __restrict__ T)       // [B][C][C] pre-zeroed
{
    const int tid  = threadIdx.x;
    const int w    = tid >> 6;         // wave id 0..3
    const int l    = tid & 63;
    const int quad = l >> 4;           // 0..3
    const int m    = l & 15;
    const int blk  = blockIdx.x;
    const int b    = blk / NCHUNK;
    const int chunk= blk % NCHUNK;

    const long pb_wave = (long)chunk * CHUNK_PX + w * 256;  // wave owns 256 px
    const float* predb = pred + (long)b * CC * HW;
    const int*   tgtb  = target + (long)b * HW;

    float4v acc00 = {0,0,0,0}, acc01 = {0,0,0,0};
    float4v acc10 = {0,0,0,0}, acc11 = {0,0,0,0};
    const short one = (short)0x3F80;   // bf16 1.0

    #pragma unroll
    for (int ks = 0; ks < 8; ++ks) {   // 8 K-steps of 32 pixels
        const long po = pb_wave + ks * 32 + quad * 8;
        const float* p0 = predb + (long)m * HW + po;        // channel m
        const float* p1 = p0 + (long)16 * HW;               // channel m+16
        const float4 a0l = *(const float4*)p0;
        const float4 a0h = *(const float4*)(p0 + 4);
        const float4 a1l = *(const float4*)p1;
        const float4 a1h = *(const float4*)(p1 + 4);
        const int4 t0 = *(const int4*)(tgtb + po);
        const int4 t1 = *(const int4*)(tgtb + po + 4);

        short8 A0, A1, B0, B1;
        A0[0]=bf16_rne(a0l.x); A0[1]=bf16_rne(a0l.y); A0[2]=bf16_rne(a0l.z); A0[3]=bf16_rne(a0l.w);
        A0[4]=bf16_rne(a0h.x); A0[5]=bf16_rne(a0h.y); A0[6]=bf16_rne(a0h.z); A0[7]=bf16_rne(a0h.w);
        A1[0]=bf16_rne(a1l.x); A1[1]=bf16_rne(a1l.y); A1[2]=bf16_rne(a1l.z); A1[3]=bf16_rne(a1l.w);
        A1[4]=bf16_rne(a1h.x); A1[5]=bf16_rne(a1h.y); A1[6]=bf16_rne(a1h.z); A1[7]=bf16_rne(a1h.w);
        // one-hot B fragments: B[k=quad*8+j][n], n = m (tile0) / m+16 (tile1)
        B0[0]=(t0.x==m)?one:(short)0; B0[1]=(t0.y==m)?one:(short)0;
        B0[2]=(t0.z==m)?one:(short)0; B0[3]=(t0.w==m)?one:(short)0;
        B0[4]=(t1.x==m)?one:(short)0; B0[5]=(t1.y==m)?one:(short)0;
        B0[6]=(t1.z==m)?one:(short)0; B0[7]=(t1.w==m)?one:(short)0;
        const int m16 = m + 16;
        B1[0]=(t0.x==m16)?one:(short)0; B1[1]=(t0.y==m16)?one:(short)0;
        B1[2]=(t0.z==m16)?one:(short)0; B1[3]=(t0.w==m16)?one:(short)0;
        B1[4]=(t1.x==m16)?one:(short)0; B1[5]=(t1.y==m16)?one:(short)0;
        B1[6]=(t1.z==m16)?one:(short)0; B1[7]=(t1.w==m16)?one:(short)0;

        acc00 = __builtin_amdgcn_mfma_f32_16x16x32_bf16(A0, B0, acc00, 0, 0, 0);
        acc01 = __builtin_amdgcn_mfma_f32_16x16x32_bf16(A0, B1, acc01, 0, 0, 0);
        acc10 = __builtin_amdgcn_mfma_f32_16x16x32_bf16(A1, B0, acc10, 0, 0, 0);
        acc11 = __builtin_amdgcn_mfma_f32_16x16x32_bf16(A1, B1, acc11, 0, 0, 0);
    }

    // cross-wave reduce in LDS (no atomics), then one global atomic per entry
    __shared__ float red[4][CC][CC];   // 16 KB
    #pragma unroll
    for (int r = 0; r < 4; ++r) {      // C layout: row=quad*4+r, col=m (m89-verified)
        red[w][quad*4 + r     ][m     ] = acc00[r];
        red[w][quad*4 + r     ][m + 16] = acc01[r];
        red[w][quad*4 + r + 16][m     ] = acc10[r];
        red[w][quad*4 + r + 16][m + 16] = acc11[r];
    }
    __syncthreads();

    float* Tb = T + (long)b * CC * CC;
    const float* rp = &red[0][0][0];
    for (int j = tid; j < CC * CC; j += 256) {
        const float s = rp[j] + rp[1024 + j] + rp[2048 + j] + rp[3072 + j];
        atomicAdd(&Tb[j], s);
    }
}

__global__ __launch_bounds__(256) void jloss_cnt(
    const int* __restrict__ target,    // [B][HW]
    float*     __restrict__ cnt)       // [B][C] pre-zeroed
{
    const int tid = threadIdx.x;
    const int w = tid >> 6, l = tid & 63;
    const int blk = blockIdx.x;
    const int b   = blk / HIST_BPB;
    const int seg = blk % HIST_BPB;
    const int* tb = target + (long)b * HW + (long)seg * HIST_SEG + w * (HIST_SEG / 4);

    int c[CC];
    #pragma unroll
    for (int k = 0; k < CC; ++k) c[k] = 0;
    for (int it = 0; it < HIST_SEG / 4 / 64; ++it) {  // 36 iters
        const int t = tb[it * 64 + l];
        #pragma unroll
        for (int k = 0; k < CC; ++k)
            c[k] += (int)__popcll(__ballot(t == k));  // wave-uniform
    }
    if (l == 0) {
        #pragma unroll
        for (int k = 0; k < CC; ++k)
            atomicAdd(&cnt[b * CC + k], (float)c[k]);
    }
}

__global__ __launch_bounds__(256) void jloss_final(
    const float* __restrict__ T,
    const float* __restrict__ cnt,
    float*       __restrict__ out)
{
    const int b   = blockIdx.x;
    const int tid = threadIdx.x;
    __shared__ float diag_s[CC];
    __shared__ float inv_n[CC];
    __shared__ float wsum[4];

    const float* Tb = T + (long)b * CC * CC;
    const float* cb = cnt + b * CC;

    if (tid < CC) {
        const float inv = 1.0f / cb[tid];
        inv_n[tid]  = inv;
        diag_s[tid] = Tb[tid * CC + tid] * inv;
    }
    __syncthreads();

    float sum = 0.0f;
    for (int idx = tid; idx < CC * CC; idx += 256) {
        const int i = idx >> 5;
        const int k = idx & 31;
        if (i != k) {
            const float S = Tb[idx] * inv_n[k];
            sum += logf(0.5f + 0.5f * (diag_s[i] - S));
        }
    }
    #pragma unroll
    for (int off = 32; off > 0; off >>= 1) sum += __shfl_down(sum, off, 64);
    if ((tid & 63) == 0) wsum[tid >> 6] = sum;
    __syncthreads();
    if (tid == 0) out[b] = -(wsum[0] + wsum[1] + wsum[2] + wsum[3]);
}

extern "C" void kernel_launch(void* const* d_in, const int* in_sizes, int n_in,
                              void* d_out, int out_size, void* d_ws, size_t ws_size,
                              hipStream_t stream) {
    const float* pred   = (const float*)d_in[0];
    const int*   target = (const int*)d_in[1];
    float* out = (float*)d_out;

    float* T   = (float*)d_ws;                       // 8*32*32 = 8192 floats
    float* cnt = (float*)d_ws + BB * CC * CC;        // 8*32    = 256 floats

    hipMemsetAsync(d_ws, 0, (BB * CC * CC + BB * CC) * sizeof(float), stream);

    jloss_cnt <<<BB * HIST_BPB, 256, 0, stream>>>(target, cnt);
    jloss_mfma<<<BB * NCHUNK,   256, 0, stream>>>(pred, target, T);
    jloss_final<<<BB, 256, 0, stream>>>(T, cnt, out);
}

// Round 3
// 222.477 us; speedup vs baseline: 1.6759x; 1.2063x over previous
//
#include <hip/hip_runtime.h>

// J-loss via MFMA: T[b,i,k] = sum_p pred[b,i,p] * onehot(target[b,p]==k)
// j[b] = -sum_{i!=k} log(0.5 + 0.5*(T[b,i,i]/n[b,i] - T[b,i,k]/n[b,k]))
//
// R2 post-mortem: full unroll hoisted ~48 dwordx4 loads -> VGPR blowout/spills.
// R3: unroll 2 + launch_bounds(256,4) (VGPR<=128); A-pack via v_perm trunc
// (1 instr / 2 elems); class counts fused via mfma(ONES, B) -> cnt kernel gone.

#define BB 8
#define CC 32
#define HW 147456                 // 384*384
#define CHUNK_PX 1024             // pixels per block (4 waves x 256 px)
#define NCHUNK (HW / CHUNK_PX)    // 144

typedef __attribute__((ext_vector_type(8))) short short8;
typedef __attribute__((ext_vector_type(4))) float float4v;
typedef __attribute__((ext_vector_type(4))) unsigned uint4v;

// pack trunc-bf16(lo), trunc-bf16(hi) into one dword: 1 v_perm_b32
__device__ __forceinline__ unsigned pk(float lo, float hi) {
    return __builtin_amdgcn_perm(__float_as_uint(hi), __float_as_uint(lo), 0x07060302u);
}
// packed pair of one-hot bf16 values for classes (ta,tb) vs m
__device__ __forceinline__ unsigned oh2(int ta, int tb, int m) {
    return (ta == m ? 0x3F80u : 0u) | (tb == m ? 0x3F800000u : 0u);
}

__global__ __launch_bounds__(256, 4) void jloss_mfma(
    const float* __restrict__ pred,    // [B][C][HW]
    const int*   __restrict__ target,  // [B][HW]
    float*       __restrict__ T,       // [B][C][C] pre-zeroed
    float*       __restrict__ cnt)     // [B][C]    pre-zeroed
{
    const int tid  = threadIdx.x;
    const int w    = tid >> 6;         // wave 0..3
    const int l    = tid & 63;
    const int quad = l >> 4;
    const int m    = l & 15;
    const int blk  = blockIdx.x;
    const int b    = blk / NCHUNK;
    const int chunk= blk % NCHUNK;

    const long pb_wave = (long)chunk * CHUNK_PX + w * 256;
    const float* predb = pred + (long)b * CC * HW;
    const int*   tgtb  = target + (long)b * HW;

    float4v acc00 = {0,0,0,0}, acc01 = {0,0,0,0};
    float4v acc10 = {0,0,0,0}, acc11 = {0,0,0,0};
    float4v accc0 = {0,0,0,0}, accc1 = {0,0,0,0};   // counts: ones . B
    const short8 ONES = {0x3F80,0x3F80,0x3F80,0x3F80,0x3F80,0x3F80,0x3F80,0x3F80};

    #pragma unroll 2
    for (int ks = 0; ks < 8; ++ks) {   // 8 K-steps of 32 pixels
        const long po = pb_wave + ks * 32 + quad * 8;
        const float* p0 = predb + (long)m * HW + po;   // channel m
        const float* p1 = p0 + (long)16 * HW;          // channel m+16
        const float4 a0l = *(const float4*)p0;
        const float4 a0h = *(const float4*)(p0 + 4);
        const float4 a1l = *(const float4*)p1;
        const float4 a1h = *(const float4*)(p1 + 4);
        const int4 t0 = *(const int4*)(tgtb + po);
        const int4 t1 = *(const int4*)(tgtb + po + 4);

        union { short8 s; uint4v u; } A0, A1, B0, B1;
        A0.u[0] = pk(a0l.x, a0l.y); A0.u[1] = pk(a0l.z, a0l.w);
        A0.u[2] = pk(a0h.x, a0h.y); A0.u[3] = pk(a0h.z, a0h.w);
        A1.u[0] = pk(a1l.x, a1l.y); A1.u[1] = pk(a1l.z, a1l.w);
        A1.u[2] = pk(a1h.x, a1h.y); A1.u[3] = pk(a1h.z, a1h.w);
        B0.u[0] = oh2(t0.x, t0.y, m);      B0.u[1] = oh2(t0.z, t0.w, m);
        B0.u[2] = oh2(t1.x, t1.y, m);      B0.u[3] = oh2(t1.z, t1.w, m);
        const int m16 = m + 16;
        B1.u[0] = oh2(t0.x, t0.y, m16);    B1.u[1] = oh2(t0.z, t0.w, m16);
        B1.u[2] = oh2(t1.x, t1.y, m16);    B1.u[3] = oh2(t1.z, t1.w, m16);

        acc00 = __builtin_amdgcn_mfma_f32_16x16x32_bf16(A0.s, B0.s, acc00, 0, 0, 0);
        acc01 = __builtin_amdgcn_mfma_f32_16x16x32_bf16(A0.s, B1.s, acc01, 0, 0, 0);
        acc10 = __builtin_amdgcn_mfma_f32_16x16x32_bf16(A1.s, B0.s, acc10, 0, 0, 0);
        acc11 = __builtin_amdgcn_mfma_f32_16x16x32_bf16(A1.s, B1.s, acc11, 0, 0, 0);
        accc0 = __builtin_amdgcn_mfma_f32_16x16x32_bf16(ONES, B0.s, accc0, 0, 0, 0);
        accc1 = __builtin_amdgcn_mfma_f32_16x16x32_bf16(ONES, B1.s, accc1, 0, 0, 0);
    }

    // cross-wave reduce in LDS, then one global atomic per entry
    __shared__ float red[4][CC][CC];   // 16 KB
    __shared__ float redc[4][CC];
    #pragma unroll
    for (int r = 0; r < 4; ++r) {      // C layout: row=quad*4+r, col=m (m89-verified)
        red[w][quad*4 + r     ][m     ] = acc00[r];
        red[w][quad*4 + r     ][m + 16] = acc01[r];
        red[w][quad*4 + r + 16][m     ] = acc10[r];
        red[w][quad*4 + r + 16][m + 16] = acc11[r];
    }
    if (quad == 0) {                   // counts: every row of accc is count[col]
        redc[w][m]      = accc0[0];
        redc[w][m + 16] = accc1[0];
    }
    __syncthreads();

    float* Tb = T + (long)b * CC * CC;
    const float* rp = &red[0][0][0];
    for (int j = tid; j < CC * CC; j += 256) {
        const float s = rp[j] + rp[1024 + j] + rp[2048 + j] + rp[3072 + j];
        atomicAdd(&Tb[j], s);
    }
    if (tid < CC)
        atomicAdd(&cnt[b * CC + tid],
                  redc[0][tid] + redc[1][tid] + redc[2][tid] + redc[3][tid]);
}

__global__ __launch_bounds__(256) void jloss_final(
    const float* __restrict__ T,
    const float* __restrict__ cnt,
    float*       __restrict__ out)
{
    const int b   = blockIdx.x;
    const int tid = threadIdx.x;
    __shared__ float diag_s[CC];
    __shared__ float inv_n[CC];
    __shared__ float wsum[4];

    const float* Tb = T + (long)b * CC * CC;
    const float* cb = cnt + b * CC;

    if (tid < CC) {
        const float inv = 1.0f / cb[tid];
        inv_n[tid]  = inv;
        diag_s[tid] = Tb[tid * CC + tid] * inv;
    }
    __syncthreads();

    float sum = 0.0f;
    for (int idx = tid; idx < CC * CC; idx += 256) {
        const int i = idx >> 5;
        const int k = idx & 31;
        if (i != k) {
            const float S = Tb[idx] * inv_n[k];
            sum += logf(0.5f + 0.5f * (diag_s[i] - S));
        }
    }
    #pragma unroll
    for (int off = 32; off > 0; off >>= 1) sum += __shfl_down(sum, off, 64);
    if ((tid & 63) == 0) wsum[tid >> 6] = sum;
    __syncthreads();
    if (tid == 0) out[b] = -(wsum[0] + wsum[1] + wsum[2] + wsum[3]);
}

extern "C" void kernel_launch(void* const* d_in, const int* in_sizes, int n_in,
                              void* d_out, int out_size, void* d_ws, size_t ws_size,
                              hipStream_t stream) {
    const float* pred   = (const float*)d_in[0];
    const int*   target = (const int*)d_in[1];
    float* out = (float*)d_out;

    float* T   = (float*)d_ws;                       // 8*32*32 floats
    float* cnt = (float*)d_ws + BB * CC * CC;        // 8*32 floats

    hipMemsetAsync(d_ws, 0, (BB * CC * CC + BB * CC) * sizeof(float), stream);

    jloss_mfma <<<BB * NCHUNK, 256, 0, stream>>>(pred, target, T, cnt);
    jloss_final<<<BB, 256, 0, stream>>>(T, cnt, out);
}